// Round 1
// baseline (93.011 us; speedup 1.0000x reference)
//
#include <hip/hip_runtime.h>
#include <math.h>

#define N_G   1024
#define IMG_H 256
#define IMG_W 256
#define G_EPS 1e-4f

// ---------------------------------------------------------------------------
// Kernel 1: per-gaussian projection + conic precompute + stable depth sort
// (O(N^2) rank count == stable ascending argsort) + scatter into sorted AoS.
// Record layout (12 floats, 48B, 16B-aligned):
//   [0] mean_x [1] mean_y [2] 0.5*d*invdet [3] 0.5*(b+c)*invdet
//   [4] 0.5*a*invdet [5] premult(=opac*normalizer*valid) [6..8] rgb [9..11] pad
// ---------------------------------------------------------------------------
__global__ __launch_bounds__(N_G) void prep_sort_kernel(
    const float* __restrict__ means3D,
    const float* __restrict__ covs3d,
    const float* __restrict__ colors,
    const float* __restrict__ opacities,
    const float* __restrict__ Km,
    const float* __restrict__ Rm,
    const float* __restrict__ tv,
    float* __restrict__ gp)
{
    const int i = threadIdx.x;

    const float m0 = means3D[i*3+0], m1 = means3D[i*3+1], m2 = means3D[i*3+2];
    const float R00=Rm[0],R01=Rm[1],R02=Rm[2];
    const float R10=Rm[3],R11=Rm[4],R12=Rm[5];
    const float R20=Rm[6],R21=Rm[7],R22=Rm[8];
    const float t0=tv[0],t1=tv[1],t2=tv[2];

    const float camx = R00*m0 + R01*m1 + R02*m2 + t0;
    const float camy = R10*m0 + R11*m1 + R12*m2 + t1;
    const float camz = R20*m0 + R21*m1 + R22*m2 + t2;
    const float depth = fmaxf(camz, 1.0f);

    const float K00=Km[0],K01=Km[1],K02=Km[2];
    const float K10=Km[3],K11=Km[4],K12=Km[5];
    const float K20=Km[6],K21=Km[7],K22=Km[8];

    const float u = K00*camx + K01*camy + K02*camz;
    const float v = K10*camx + K11*camy + K12*camz;
    const float z = K20*camx + K21*camy + K22*camz;

    const float mx = u / z;
    const float my = v / z;

    const float inv_z2 = 1.0f / (z*z);
    const float J00 = K00/z - u*inv_z2;
    const float J01 = K01/z - v*inv_z2;
    const float J02 = -u*inv_z2;
    const float J10 = K10/z - u*inv_z2;
    const float J11 = K11/z - v*inv_z2;
    const float J12 = -v*inv_z2;

    const float* S = covs3d + i*9;
    const float S00=S[0],S01=S[1],S02=S[2];
    const float S10=S[3],S11=S[4],S12=S[5];
    const float S20=S[6],S21=S[7],S22=S[8];

    // M = R*S
    const float M00 = R00*S00 + R01*S10 + R02*S20;
    const float M01 = R00*S01 + R01*S11 + R02*S21;
    const float M02 = R00*S02 + R01*S12 + R02*S22;
    const float M10 = R10*S00 + R11*S10 + R12*S20;
    const float M11 = R10*S01 + R11*S11 + R12*S21;
    const float M12 = R10*S02 + R11*S12 + R12*S22;
    const float M20 = R20*S00 + R21*S10 + R22*S20;
    const float M21 = R20*S01 + R21*S11 + R22*S21;
    const float M22 = R20*S02 + R21*S12 + R22*S22;

    // C = M*R^T
    const float C00 = M00*R00 + M01*R01 + M02*R02;
    const float C01 = M00*R10 + M01*R11 + M02*R12;
    const float C02 = M00*R20 + M01*R21 + M02*R22;
    const float C10 = M10*R00 + M11*R01 + M12*R02;
    const float C11 = M10*R10 + M11*R11 + M12*R12;
    const float C12 = M10*R20 + M11*R21 + M12*R22;
    const float C20 = M20*R00 + M21*R01 + M22*R02;
    const float C21 = M20*R10 + M21*R11 + M22*R12;
    const float C22 = M20*R20 + M21*R21 + M22*R22;

    // JC = J*C  (2x3)
    const float JC00 = J00*C00 + J01*C10 + J02*C20;
    const float JC01 = J00*C01 + J01*C11 + J02*C21;
    const float JC02 = J00*C02 + J01*C12 + J02*C22;
    const float JC10 = J10*C00 + J11*C10 + J12*C20;
    const float JC11 = J10*C01 + J11*C11 + J12*C21;
    const float JC12 = J10*C02 + J11*C12 + J12*C22;

    // V = JC*J^T (2x2) + EPS*I
    const float a = JC00*J00 + JC01*J01 + JC02*J02 + G_EPS;
    const float b = JC00*J10 + JC01*J11 + JC02*J12;
    const float c = JC10*J00 + JC11*J01 + JC12*J02;
    const float d = JC10*J10 + JC11*J11 + JC12*J12 + G_EPS;

    const float det = a*d - b*c;
    const float inv_det = 1.0f / det;
    const bool valid = (depth > 1.0f) && (depth < 50.0f);
    const float normalizer = 0.15915494309189535f / sqrtf(det); // 1/(2*pi*sqrt(det))
    const float premult = valid ? (opacities[i] * normalizer) : 0.0f;

    // ---- stable ascending rank (== jnp.argsort, stable) ----
    __shared__ float sd[N_G];
    sd[i] = depth;
    __syncthreads();
    const float di = depth;
    int rank = 0;
    for (int j = 0; j < N_G; j += 4) {
        const float4 d4 = *(const float4*)&sd[j];
        rank += (d4.x < di) || (d4.x == di && (j+0) < i);
        rank += (d4.y < di) || (d4.y == di && (j+1) < i);
        rank += (d4.z < di) || (d4.z == di && (j+2) < i);
        rank += (d4.w < di) || (d4.w == di && (j+3) < i);
    }

    float* o = gp + rank*12;
    o[0]  = mx;
    o[1]  = my;
    o[2]  = 0.5f * d * inv_det;
    o[3]  = 0.5f * (b + c) * inv_det;
    o[4]  = 0.5f * a * inv_det;
    o[5]  = premult;
    o[6]  = colors[i*3+0];
    o[7]  = colors[i*3+1];
    o[8]  = colors[i*3+2];
    o[9]  = 0.0f;
    o[10] = 0.0f;
    o[11] = 0.0f;
}

// ---------------------------------------------------------------------------
// Kernel 2: per-pixel front-to-back compositing over sorted gaussians.
// 256 blocks (16x16 tiles of 16x16 pixels), 256 threads = 1 pixel/thread.
// Gaussians staged in 256-chunk LDS buffers; inner reads are uniform-address
// broadcasts (conflict-free).
// ---------------------------------------------------------------------------
__global__ __launch_bounds__(256) void render_kernel(
    const float* __restrict__ gp, float* __restrict__ out)
{
    const int lx = threadIdx.x & 15;
    const int ly = threadIdx.x >> 4;
    const int px = ((blockIdx.x & 15) << 4) + lx;
    const int py = ((blockIdx.x >> 4) << 4) + ly;
    const float fpx = (float)px, fpy = (float)py;

    __shared__ float sg[256 * 12];

    float T = 1.0f, cr = 0.0f, cg = 0.0f, cb = 0.0f;

    for (int base = 0; base < N_G; base += 256) {
        __syncthreads();
        const float* src = gp + base * 12;
        #pragma unroll
        for (int f = 0; f < 12; ++f)
            sg[f*256 + threadIdx.x] = src[f*256 + threadIdx.x];
        __syncthreads();

        #pragma unroll 4
        for (int k = 0; k < 256; ++k) {
            const float* g = &sg[k*12];
            const float dx = fpx - g[0];
            const float dy = fpy - g[1];
            const float P = -(g[2]*dx*dx - g[3]*dx*dy + g[4]*dy*dy);
            const float alpha = g[5] * __expf(P);
            const float w = T * alpha;
            cr = fmaf(w, g[6], cr);
            cg = fmaf(w, g[7], cg);
            cb = fmaf(w, g[8], cb);
            T -= w;   // T*(1-alpha)
        }
    }

    const int pid = py * IMG_W + px;
    out[pid*3 + 0] = cr;
    out[pid*3 + 1] = cg;
    out[pid*3 + 2] = cb;
}

extern "C" void kernel_launch(void* const* d_in, const int* in_sizes, int n_in,
                              void* d_out, int out_size, void* d_ws, size_t ws_size,
                              hipStream_t stream) {
    const float* means3D   = (const float*)d_in[0];
    const float* covs3d    = (const float*)d_in[1];
    const float* colors    = (const float*)d_in[2];
    const float* opacities = (const float*)d_in[3];
    const float* Km        = (const float*)d_in[4];
    const float* Rm        = (const float*)d_in[5];
    const float* tv        = (const float*)d_in[6];

    float* gp = (float*)d_ws;   // 1024 * 12 floats = 48 KB

    hipLaunchKernelGGL(prep_sort_kernel, dim3(1), dim3(N_G), 0, stream,
                       means3D, covs3d, colors, opacities, Km, Rm, tv, gp);
    hipLaunchKernelGGL(render_kernel, dim3(256), dim3(256), 0, stream,
                       gp, (float*)d_out);
}

// Round 2
// 43.966 us; speedup vs baseline: 2.1155x; 2.1155x over previous
//
#include <hip/hip_runtime.h>
#include <math.h>

#define N_G   1024
#define IMG_H 256
#define IMG_W 256
#define G_EPS 1e-4f
#define LOG2E 1.4426950408889634f

// ---------------------------------------------------------------------------
// Kernel 1: projection + conic precompute + stable depth-rank + scatter.
// Grid: 16 blocks x 256 threads; block b owns gaussians [b*64, b*64+64).
// Record layout (12 floats, 48B):
//   [0] mean_x [1] mean_y
//   [2] c2 = -0.5*d*invdet*LOG2E   (coeff of dx^2, log2 domain, negated)
//   [3] c3 = +0.5*(b+c)*invdet*LOG2E (coeff of dx*dy)
//   [4] c4 = -0.5*a*invdet*LOG2E   (coeff of dy^2)
//   [5] premult = valid * opacity / (2*pi*sqrt(det))
//   [6..8] rgb   [9..11] pad
// ---------------------------------------------------------------------------
__global__ __launch_bounds__(256) void prep_sort_kernel(
    const float* __restrict__ means3D,
    const float* __restrict__ covs3d,
    const float* __restrict__ colors,
    const float* __restrict__ opacities,
    const float* __restrict__ Km,
    const float* __restrict__ Rm,
    const float* __restrict__ tv,
    float* __restrict__ gp)
{
    __shared__ alignas(16) float sd[N_G];
    __shared__ int pr[4][64];

    const int t = threadIdx.x;
    const int b = blockIdx.x;

    const float R20=Rm[6],R21=Rm[7],R22=Rm[8];
    const float t2=tv[2];

    // phase 1: all 1024 depths, 4 per thread (coalesced over g)
    #pragma unroll
    for (int k = 0; k < 4; ++k) {
        const int g = t + 256*k;
        const float m0 = means3D[g*3+0], m1 = means3D[g*3+1], m2 = means3D[g*3+2];
        sd[g] = fmaxf(R20*m0 + R21*m1 + R22*m2 + t2, 1.0f);
    }
    __syncthreads();

    // phase 2: partial stable ranks. thread t: gaussian li = t&63, quarter q = t>>6
    const int li = t & 63;
    const int q  = t >> 6;
    const int i  = b*64 + li;
    const float di = sd[i];
    int rank = 0;
    const int j0 = q*256;
    for (int j = j0; j < j0 + 256; j += 4) {
        const float4 d4 = *(const float4*)&sd[j];
        rank += (d4.x < di) || (d4.x == di && (j+0) < i);
        rank += (d4.y < di) || (d4.y == di && (j+1) < i);
        rank += (d4.z < di) || (d4.z == di && (j+2) < i);
        rank += (d4.w < di) || (d4.w == di && (j+3) < i);
    }
    pr[q][li] = rank;
    __syncthreads();

    // phase 3: first 64 threads do full projection + write sorted record
    if (t < 64) {
        const int gi = b*64 + t;
        const int r  = pr[0][t] + pr[1][t] + pr[2][t] + pr[3][t];

        const float m0 = means3D[gi*3+0], m1 = means3D[gi*3+1], m2 = means3D[gi*3+2];
        const float R00=Rm[0],R01=Rm[1],R02=Rm[2];
        const float R10=Rm[3],R11=Rm[4],R12=Rm[5];
        const float t0=tv[0],t1=tv[1];

        const float camx = R00*m0 + R01*m1 + R02*m2 + t0;
        const float camy = R10*m0 + R11*m1 + R12*m2 + t1;
        const float camz = R20*m0 + R21*m1 + R22*m2 + t2;
        const float depth = fmaxf(camz, 1.0f);

        const float K00=Km[0],K01=Km[1],K02=Km[2];
        const float K10=Km[3],K11=Km[4],K12=Km[5];
        const float K20=Km[6],K21=Km[7],K22=Km[8];

        const float u = K00*camx + K01*camy + K02*camz;
        const float v = K10*camx + K11*camy + K12*camz;
        const float z = K20*camx + K21*camy + K22*camz;

        const float mx = u / z;
        const float my = v / z;

        const float inv_z2 = 1.0f / (z*z);
        const float J00 = K00/z - u*inv_z2;
        const float J01 = K01/z - v*inv_z2;
        const float J02 = -u*inv_z2;
        const float J10 = K10/z - u*inv_z2;
        const float J11 = K11/z - v*inv_z2;
        const float J12 = -v*inv_z2;

        const float* S = covs3d + gi*9;
        const float S00=S[0],S01=S[1],S02=S[2];
        const float S10=S[3],S11=S[4],S12=S[5];
        const float S20=S[6],S21=S[7],S22=S[8];

        // M = R*S
        const float M00 = R00*S00 + R01*S10 + R02*S20;
        const float M01 = R00*S01 + R01*S11 + R02*S21;
        const float M02 = R00*S02 + R01*S12 + R02*S22;
        const float M10 = R10*S00 + R11*S10 + R12*S20;
        const float M11 = R10*S01 + R11*S11 + R12*S21;
        const float M12 = R10*S02 + R11*S12 + R12*S22;
        const float M20 = R20*S00 + R21*S10 + R22*S20;
        const float M21 = R20*S01 + R21*S11 + R22*S21;
        const float M22 = R20*S02 + R21*S12 + R22*S22;

        // C = M*R^T
        const float C00 = M00*R00 + M01*R01 + M02*R02;
        const float C01 = M00*R10 + M01*R11 + M02*R12;
        const float C02 = M00*R20 + M01*R21 + M02*R22;
        const float C10 = M10*R00 + M11*R01 + M12*R02;
        const float C11 = M10*R10 + M11*R11 + M12*R12;
        const float C12 = M10*R20 + M11*R21 + M12*R22;
        const float C20 = M20*R00 + M21*R01 + M22*R02;
        const float C21 = M20*R10 + M21*R11 + M22*R12;
        const float C22 = M20*R20 + M21*R21 + M22*R22;

        // JC = J*C (2x3)
        const float JC00 = J00*C00 + J01*C10 + J02*C20;
        const float JC01 = J00*C01 + J01*C11 + J02*C21;
        const float JC02 = J00*C02 + J01*C12 + J02*C22;
        const float JC10 = J10*C00 + J11*C10 + J12*C20;
        const float JC11 = J10*C01 + J11*C11 + J12*C21;
        const float JC12 = J10*C02 + J11*C12 + J12*C22;

        // V = JC*J^T + EPS*I
        const float a = JC00*J00 + JC01*J01 + JC02*J02 + G_EPS;
        const float bb= JC00*J10 + JC01*J11 + JC02*J12;
        const float c = JC10*J00 + JC11*J01 + JC12*J02;
        const float d = JC10*J10 + JC11*J11 + JC12*J12 + G_EPS;

        const float det = a*d - bb*c;
        const float inv_det = 1.0f / det;
        const bool valid = (depth > 1.0f) && (depth < 50.0f);
        const float normalizer = 0.15915494309189535f / sqrtf(det);
        const float premult = valid ? (opacities[gi] * normalizer) : 0.0f;

        float* o = gp + r*12;
        o[0]  = mx;
        o[1]  = my;
        o[2]  = -0.5f * d * inv_det * LOG2E;
        o[3]  =  0.5f * (bb + c) * inv_det * LOG2E;
        o[4]  = -0.5f * a * inv_det * LOG2E;
        o[5]  = premult;
        o[6]  = colors[gi*3+0];
        o[7]  = colors[gi*3+1];
        o[8]  = colors[gi*3+2];
        o[9]  = 0.0f;
        o[10] = 0.0f;
        o[11] = 0.0f;
    }
}

// ---------------------------------------------------------------------------
// Kernel 2: compositing. Grid 256 blocks x 1024 threads.
// Block = 16x16 pixel tile; thread t: pixel p = t&255, segment s = t>>8.
// Segment s composites gaussians [s*256, s*256+256); segments are combined
// with the associative rule C = C0 + T0*C1 + T0*T1*C2 + T0*T1*T2*C3.
// All 1024 records staged in LDS once (48KB); inner reads are wave-uniform
// broadcasts.
// ---------------------------------------------------------------------------
__global__ __launch_bounds__(1024) void render_kernel(
    const float* __restrict__ gp, float* __restrict__ out)
{
    __shared__ alignas(16) float sg[N_G * 12];   // 48 KB
    __shared__ float comb[3][4][256];            // 12 KB

    const int t = threadIdx.x;
    const int p = t & 255;
    const int s = t >> 8;
    const int px = ((blockIdx.x & 15) << 4) + (p & 15);
    const int py = ((blockIdx.x >> 4) << 4) + (p >> 4);
    const float fpx = (float)px, fpy = (float)py;

    for (int idx = t; idx < N_G * 12; idx += 1024)
        sg[idx] = gp[idx];
    __syncthreads();

    float T = 1.0f, cr = 0.0f, cg = 0.0f, cb = 0.0f;
    const float* gbase = &sg[s * 256 * 12];

    #pragma unroll 4
    for (int k = 0; k < 256; ++k) {
        const float* g = gbase + k*12;
        const float dx = fpx - g[0];
        const float dy = fpy - g[1];
        float q1 = fmaf(g[3], dy, g[2]*dx);          // c2*dx + c3*dy
        float P2 = fmaf(g[4]*dy, dy, dx*q1);         // log2-domain exponent
        const float alpha = g[5] * __builtin_amdgcn_exp2f(P2);
        const float w = T * alpha;
        cr = fmaf(w, g[6], cr);
        cg = fmaf(w, g[7], cg);
        cb = fmaf(w, g[8], cb);
        T  = fmaf(-alpha, T, T);                     // T *= (1 - alpha)
    }

    if (s > 0) {
        comb[s-1][0][p] = T;
        comb[s-1][1][p] = cr;
        comb[s-1][2][p] = cg;
        comb[s-1][3][p] = cb;
    }
    __syncthreads();

    if (s == 0) {
        #pragma unroll
        for (int si = 0; si < 3; ++si) {
            cr = fmaf(T, comb[si][1][p], cr);
            cg = fmaf(T, comb[si][2][p], cg);
            cb = fmaf(T, comb[si][3][p], cb);
            T *= comb[si][0][p];
        }
        const int pid = py * IMG_W + px;
        out[pid*3 + 0] = cr;
        out[pid*3 + 1] = cg;
        out[pid*3 + 2] = cb;
    }
}

extern "C" void kernel_launch(void* const* d_in, const int* in_sizes, int n_in,
                              void* d_out, int out_size, void* d_ws, size_t ws_size,
                              hipStream_t stream) {
    const float* means3D   = (const float*)d_in[0];
    const float* covs3d    = (const float*)d_in[1];
    const float* colors    = (const float*)d_in[2];
    const float* opacities = (const float*)d_in[3];
    const float* Km        = (const float*)d_in[4];
    const float* Rm        = (const float*)d_in[5];
    const float* tv        = (const float*)d_in[6];

    float* gp = (float*)d_ws;   // 1024 * 12 floats = 48 KB

    hipLaunchKernelGGL(prep_sort_kernel, dim3(16), dim3(256), 0, stream,
                       means3D, covs3d, colors, opacities, Km, Rm, tv, gp);
    hipLaunchKernelGGL(render_kernel, dim3(256), dim3(1024), 0, stream,
                       gp, (float*)d_out);
}

// Round 3
// 35.736 us; speedup vs baseline: 2.6027x; 1.2303x over previous
//
#include <hip/hip_runtime.h>
#include <math.h>

#define N_G   1024
#define IMG_H 256
#define IMG_W 256
#define G_EPS 1e-4f
#define LOG2E 1.4426950408889634f
#define TILE_RAD 10.6066017f   // 7.5*sqrt(2): max pixel distance from tile center

// ---------------------------------------------------------------------------
// Kernel 1: projection + conic precompute + cull radius + stable depth-rank +
// scatter into sorted AoS. Grid: 16 blocks x 256 threads.
// Record layout (16 floats, 64B):
//   [0] mean_x [1] mean_y
//   [2] c2 = -0.5*d*invdet*LOG2E   (coeff dx^2, log2 domain)
//   [3] c3 = +0.5*(b+c)*invdet*LOG2E (coeff dx*dy)
//   [4] c4 = -0.5*a*invdet*LOG2E   (coeff dy^2)
//   [5] premult = valid * opacity / (2*pi*sqrt(det))
//   [6] r [7] g [8] b
//   [9] rr2 = (cull_radius + TILE_RAD)^2 ; tile kept iff dist2(center,mean)<=rr2
//   [10..15] pad
// ---------------------------------------------------------------------------
__global__ __launch_bounds__(256) void prep_sort_kernel(
    const float* __restrict__ means3D,
    const float* __restrict__ covs3d,
    const float* __restrict__ colors,
    const float* __restrict__ opacities,
    const float* __restrict__ Km,
    const float* __restrict__ Rm,
    const float* __restrict__ tv,
    float* __restrict__ gp)
{
    __shared__ alignas(16) float sd[N_G];
    __shared__ int pr[4][64];

    const int t = threadIdx.x;
    const int b = blockIdx.x;

    const float R20=Rm[6],R21=Rm[7],R22=Rm[8];
    const float t2=tv[2];

    // phase 1: all 1024 depths, 4 per thread
    #pragma unroll
    for (int k = 0; k < 4; ++k) {
        const int g = t + 256*k;
        const float m0 = means3D[g*3+0], m1 = means3D[g*3+1], m2 = means3D[g*3+2];
        sd[g] = fmaxf(R20*m0 + R21*m1 + R22*m2 + t2, 1.0f);
    }
    __syncthreads();

    // phase 2: partial stable ranks (thread t: gaussian li=t&63, quarter q=t>>6)
    const int li = t & 63;
    const int q  = t >> 6;
    const int i  = b*64 + li;
    const float di = sd[i];
    int rank = 0;
    const int j0 = q*256;
    for (int j = j0; j < j0 + 256; j += 4) {
        const float4 d4 = *(const float4*)&sd[j];
        rank += (d4.x < di) || (d4.x == di && (j+0) < i);
        rank += (d4.y < di) || (d4.y == di && (j+1) < i);
        rank += (d4.z < di) || (d4.z == di && (j+2) < i);
        rank += (d4.w < di) || (d4.w == di && (j+3) < i);
    }
    pr[q][li] = rank;
    __syncthreads();

    // phase 3: first 64 threads: full projection + record at sorted position
    if (t < 64) {
        const int gi = b*64 + t;
        const int r  = pr[0][t] + pr[1][t] + pr[2][t] + pr[3][t];

        const float m0 = means3D[gi*3+0], m1 = means3D[gi*3+1], m2 = means3D[gi*3+2];
        const float R00=Rm[0],R01=Rm[1],R02=Rm[2];
        const float R10=Rm[3],R11=Rm[4],R12=Rm[5];
        const float t0=tv[0],t1=tv[1];

        const float camx = R00*m0 + R01*m1 + R02*m2 + t0;
        const float camy = R10*m0 + R11*m1 + R12*m2 + t1;
        const float camz = R20*m0 + R21*m1 + R22*m2 + t2;
        const float depth = fmaxf(camz, 1.0f);

        const float K00=Km[0],K01=Km[1],K02=Km[2];
        const float K10=Km[3],K11=Km[4],K12=Km[5];
        const float K20=Km[6],K21=Km[7],K22=Km[8];

        const float u = K00*camx + K01*camy + K02*camz;
        const float v = K10*camx + K11*camy + K12*camz;
        const float z = K20*camx + K21*camy + K22*camz;

        const float mx = u / z;
        const float my = v / z;

        const float inv_z2 = 1.0f / (z*z);
        const float J00 = K00/z - u*inv_z2;
        const float J01 = K01/z - v*inv_z2;
        const float J02 = -u*inv_z2;
        const float J10 = K10/z - u*inv_z2;
        const float J11 = K11/z - v*inv_z2;
        const float J12 = -v*inv_z2;

        const float* S = covs3d + gi*9;
        const float S00=S[0],S01=S[1],S02=S[2];
        const float S10=S[3],S11=S[4],S12=S[5];
        const float S20=S[6],S21=S[7],S22=S[8];

        // M = R*S
        const float M00 = R00*S00 + R01*S10 + R02*S20;
        const float M01 = R00*S01 + R01*S11 + R02*S21;
        const float M02 = R00*S02 + R01*S12 + R02*S22;
        const float M10 = R10*S00 + R11*S10 + R12*S20;
        const float M11 = R10*S01 + R11*S11 + R12*S21;
        const float M12 = R10*S02 + R11*S12 + R12*S22;
        const float M20 = R20*S00 + R21*S10 + R22*S20;
        const float M21 = R20*S01 + R21*S11 + R22*S21;
        const float M22 = R20*S02 + R21*S12 + R22*S22;

        // C = M*R^T
        const float C00 = M00*R00 + M01*R01 + M02*R02;
        const float C01 = M00*R10 + M01*R11 + M02*R12;
        const float C02 = M00*R20 + M01*R21 + M02*R22;
        const float C10 = M10*R00 + M11*R01 + M12*R02;
        const float C11 = M10*R10 + M11*R11 + M12*R12;
        const float C12 = M10*R20 + M11*R21 + M12*R22;
        const float C20 = M20*R00 + M21*R01 + M22*R02;
        const float C21 = M20*R10 + M21*R11 + M22*R12;
        const float C22 = M20*R20 + M21*R21 + M22*R22;

        // JC = J*C (2x3)
        const float JC00 = J00*C00 + J01*C10 + J02*C20;
        const float JC01 = J00*C01 + J01*C11 + J02*C21;
        const float JC02 = J00*C02 + J01*C12 + J02*C22;
        const float JC10 = J10*C00 + J11*C10 + J12*C20;
        const float JC11 = J10*C01 + J11*C11 + J12*C21;
        const float JC12 = J10*C02 + J11*C12 + J12*C22;

        // V = JC*J^T + EPS*I
        const float a = JC00*J00 + JC01*J01 + JC02*J02 + G_EPS;
        const float bb= JC00*J10 + JC01*J11 + JC02*J12;
        const float c = JC10*J00 + JC11*J01 + JC12*J02;
        const float d = JC10*J10 + JC11*J11 + JC12*J12 + G_EPS;

        const float det = a*d - bb*c;
        const float inv_det = 1.0f / det;
        const bool valid = (depth > 1.0f) && (depth < 50.0f);
        const float normalizer = 0.15915494309189535f / sqrtf(det);
        const float premult = valid ? (opacities[gi] * normalizer) : 0.0f;

        // cull radius: q_ln(dx) >= lambda_min*|dx|^2 for the ln-domain conic
        // Q = 0.5*invdet*[[d, -(b+c)/2],[-(b+c)/2, a]]
        const float tm   = 0.25f * inv_det * (a + d);
        const float detQ = 0.25f * inv_det * inv_det * (a*d - 0.25f*(bb+c)*(bb+c));
        const float lmin = tm - sqrtf(fmaxf(tm*tm - detQ, 0.0f));
        float rr2;
        if (premult > 0.0f && lmin > 0.0f) {
            // premult * exp(-lmin*r^2) <= 1e-9  ->  r^2 = ln(premult*1e9)/lmin
            const float r2c = fmaxf(logf(premult * 1e9f) / lmin, 0.0f);
            const float rr  = sqrtf(r2c) + TILE_RAD;
            rr2 = rr * rr;
        } else {
            rr2 = -1.0f;   // never kept
        }

        float* o = gp + r*16;
        o[0]  = mx;
        o[1]  = my;
        o[2]  = -0.5f * d * inv_det * LOG2E;
        o[3]  =  0.5f * (bb + c) * inv_det * LOG2E;
        o[4]  = -0.5f * a * inv_det * LOG2E;
        o[5]  = premult;
        o[6]  = colors[gi*3+0];
        o[7]  = colors[gi*3+1];
        o[8]  = colors[gi*3+2];
        o[9]  = rr2;
        o[10] = 0.0f; o[11] = 0.0f; o[12] = 0.0f;
        o[13] = 0.0f; o[14] = 0.0f; o[15] = 0.0f;
    }
}

// ---------------------------------------------------------------------------
// Kernel 2: per-tile cull+compact, then composite survivors.
// Grid 256 blocks x 512 threads. Block = one 16x16 pixel tile.
// Thread t: pixel p = t&255, segment s = t>>8 (2 depth-segments of the
// survivor list, combined with C = C0 + T0*C1).
// Compaction is order-preserving (ballot + prefix within/across waves).
// ---------------------------------------------------------------------------
__global__ __launch_bounds__(512) void render_kernel(
    const float* __restrict__ gp, float* __restrict__ out)
{
    __shared__ alignas(16) float sgrec[N_G * 12];  // survivor records, 48KB max
    __shared__ float comb[4][256];
    __shared__ int wc[8];

    const int t    = threadIdx.x;
    const int tile = blockIdx.x;
    const int lane = t & 63;
    const int w    = t >> 6;
    const float cx = (float)((tile & 15) * 16) + 7.5f;
    const float cy = (float)((tile >> 4) * 16) + 7.5f;

    // --- cull + order-preserving compact + stage to LDS ---
    int total = 0;
    #pragma unroll
    for (int rnd = 0; rnd < 2; ++rnd) {
        const int g = rnd * 512 + t;
        const float4 q0 = *(const float4*)(gp + g*16);     // mx,my,c2,c3
        const float rr2 = gp[g*16 + 9];
        const float dx = q0.x - cx, dy = q0.y - cy;
        const bool keep = (dx*dx + dy*dy) <= rr2;
        const unsigned long long m = __ballot(keep);
        if (lane == 0) wc[w] = __popcll(m);
        __syncthreads();
        int baseW = 0, sumAll = 0;
        #pragma unroll
        for (int i = 0; i < 8; ++i) {
            const int c = wc[i];
            if (i < w) baseW += c;
            sumAll += c;
        }
        if (keep) {
            const int pos = total + baseW +
                __popcll(m & ((1ull << lane) - 1ull));
            const float4 q1 = *(const float4*)(gp + g*16 + 4); // c4,pm,r,g
            const float bcol = gp[g*16 + 8];
            float* dst = &sgrec[pos * 12];
            *(float4*)(dst + 0) = q0;
            *(float4*)(dst + 4) = q1;
            dst[8] = bcol;
        }
        total += sumAll;
        __syncthreads();   // wc reused next round; sgrec writes drain
    }

    // --- composite survivors [k0,k1) for this segment ---
    const int p  = t & 255;
    const int s  = t >> 8;
    const int px = ((tile & 15) << 4) + (p & 15);
    const int py = ((tile >> 4) << 4) + (p >> 4);
    const float fpx = (float)px, fpy = (float)py;

    const int half = (total + 1) >> 1;
    const int k0 = s * half;
    const int k1 = (k0 + half < total) ? (k0 + half) : total;

    float T = 1.0f, cr = 0.0f, cg = 0.0f, cb = 0.0f;
    for (int k = k0; k < k1; ++k) {
        const float* g = &sgrec[k * 12];
        const float4 a0 = *(const float4*)(g + 0);  // mx,my,c2,c3
        const float4 a1 = *(const float4*)(g + 4);  // c4,pm,r,g
        const float bcol = g[8];
        const float dx = fpx - a0.x;
        const float dy = fpy - a0.y;
        const float t1 = fmaf(a0.w, dy, a0.z * dx);
        const float P2 = fmaf(dx, t1, a1.x * dy * dy);
        const float alpha = a1.y * __builtin_amdgcn_exp2f(P2);
        const float wgt = T * alpha;
        cr = fmaf(wgt, a1.z, cr);
        cg = fmaf(wgt, a1.w, cg);
        cb = fmaf(wgt, bcol, cb);
        T  = fmaf(-alpha, T, T);
    }

    if (s == 1) {
        comb[0][p] = T;
        comb[1][p] = cr;
        comb[2][p] = cg;
        comb[3][p] = cb;
    }
    __syncthreads();

    if (s == 0) {
        cr = fmaf(T, comb[1][p], cr);
        cg = fmaf(T, comb[2][p], cg);
        cb = fmaf(T, comb[3][p], cb);
        const int pid = py * IMG_W + px;
        out[pid*3 + 0] = cr;
        out[pid*3 + 1] = cg;
        out[pid*3 + 2] = cb;
    }
}

extern "C" void kernel_launch(void* const* d_in, const int* in_sizes, int n_in,
                              void* d_out, int out_size, void* d_ws, size_t ws_size,
                              hipStream_t stream) {
    const float* means3D   = (const float*)d_in[0];
    const float* covs3d    = (const float*)d_in[1];
    const float* colors    = (const float*)d_in[2];
    const float* opacities = (const float*)d_in[3];
    const float* Km        = (const float*)d_in[4];
    const float* Rm        = (const float*)d_in[5];
    const float* tv        = (const float*)d_in[6];

    float* gp = (float*)d_ws;   // 1024 * 16 floats = 64 KB

    hipLaunchKernelGGL(prep_sort_kernel, dim3(16), dim3(256), 0, stream,
                       means3D, covs3d, colors, opacities, Km, Rm, tv, gp);
    hipLaunchKernelGGL(render_kernel, dim3(256), dim3(512), 0, stream,
                       gp, (float*)d_out);
}

// Round 4
// 22.825 us; speedup vs baseline: 4.0750x; 1.5656x over previous
//
#include <hip/hip_runtime.h>
#include <math.h>

#define N_G   1024
#define IMG_H 256
#define IMG_W 256
#define G_EPS 1e-4f
#define LOG2E 1.4426950408889634f
#define TILE_RAD 4.9497475f    // 3.5*sqrt(2): max pixel distance from 8x8 tile center
#define CULL_INV_EPS 5.0e6f    // 1/eps, eps = 2e-7 contribution cutoff

// ws layout:
//   gp[0    ..2047]  : float2 mean[1024]      (sorted order)
//   gp[2048 ..3071]  : float  rr2[1024]       (cull radius^2, incl. TILE_RAD)
//   gp[3072 ..15359] : float  rec[1024][12]:
//     [0] mean_x [1] mean_y
//     [2] c2 = -0.5*d*invdet*LOG2E     (dx^2 coeff, log2 domain)
//     [3] c3 = +0.5*(b+c)*invdet*LOG2E (dx*dy coeff)
//     [4] c4 = -0.5*a*invdet*LOG2E     (dy^2 coeff)
//     [5] c5 = log2(premult)           (folded into exponent)
//     [6] r [7] g [8] b  [9..11] pad
// ---------------------------------------------------------------------------
__global__ __launch_bounds__(256) void prep_sort_kernel(
    const float* __restrict__ means3D,
    const float* __restrict__ covs3d,
    const float* __restrict__ colors,
    const float* __restrict__ opacities,
    const float* __restrict__ Km,
    const float* __restrict__ Rm,
    const float* __restrict__ tv,
    float* __restrict__ gp)
{
    __shared__ alignas(16) float sd[N_G];
    __shared__ int pr[4][64];

    const int t = threadIdx.x;
    const int b = blockIdx.x;

    const float R20=Rm[6],R21=Rm[7],R22=Rm[8];
    const float t2=tv[2];

    // phase 1: all 1024 depths, 4 per thread
    #pragma unroll
    for (int k = 0; k < 4; ++k) {
        const int g = t + 256*k;
        const float m0 = means3D[g*3+0], m1 = means3D[g*3+1], m2 = means3D[g*3+2];
        sd[g] = fmaxf(R20*m0 + R21*m1 + R22*m2 + t2, 1.0f);
    }
    __syncthreads();

    // phase 2: partial stable ranks (thread t: gaussian li=t&63, quarter q=t>>6)
    const int li = t & 63;
    const int q  = t >> 6;
    const int i  = b*64 + li;
    const float di = sd[i];
    int rank = 0;
    const int j0 = q*256;
    for (int j = j0; j < j0 + 256; j += 4) {
        const float4 d4 = *(const float4*)&sd[j];
        rank += (d4.x < di) || (d4.x == di && (j+0) < i);
        rank += (d4.y < di) || (d4.y == di && (j+1) < i);
        rank += (d4.z < di) || (d4.z == di && (j+2) < i);
        rank += (d4.w < di) || (d4.w == di && (j+3) < i);
    }
    pr[q][li] = rank;
    __syncthreads();

    // phase 3: first 64 threads: full projection + record at sorted position
    if (t < 64) {
        const int gi = b*64 + t;
        const int r  = pr[0][t] + pr[1][t] + pr[2][t] + pr[3][t];

        const float m0 = means3D[gi*3+0], m1 = means3D[gi*3+1], m2 = means3D[gi*3+2];
        const float R00=Rm[0],R01=Rm[1],R02=Rm[2];
        const float R10=Rm[3],R11=Rm[4],R12=Rm[5];
        const float t0=tv[0],t1=tv[1];

        const float camx = R00*m0 + R01*m1 + R02*m2 + t0;
        const float camy = R10*m0 + R11*m1 + R12*m2 + t1;
        const float camz = R20*m0 + R21*m1 + R22*m2 + t2;
        const float depth = fmaxf(camz, 1.0f);

        const float K00=Km[0],K01=Km[1],K02=Km[2];
        const float K10=Km[3],K11=Km[4],K12=Km[5];
        const float K20=Km[6],K21=Km[7],K22=Km[8];

        const float u = K00*camx + K01*camy + K02*camz;
        const float v = K10*camx + K11*camy + K12*camz;
        const float z = K20*camx + K21*camy + K22*camz;

        const float mx = u / z;
        const float my = v / z;

        const float inv_z2 = 1.0f / (z*z);
        const float J00 = K00/z - u*inv_z2;
        const float J01 = K01/z - v*inv_z2;
        const float J02 = -u*inv_z2;
        const float J10 = K10/z - u*inv_z2;
        const float J11 = K11/z - v*inv_z2;
        const float J12 = -v*inv_z2;

        const float* S = covs3d + gi*9;
        const float S00=S[0],S01=S[1],S02=S[2];
        const float S10=S[3],S11=S[4],S12=S[5];
        const float S20=S[6],S21=S[7],S22=S[8];

        // M = R*S
        const float M00 = R00*S00 + R01*S10 + R02*S20;
        const float M01 = R00*S01 + R01*S11 + R02*S21;
        const float M02 = R00*S02 + R01*S12 + R02*S22;
        const float M10 = R10*S00 + R11*S10 + R12*S20;
        const float M11 = R10*S01 + R11*S11 + R12*S21;
        const float M12 = R10*S02 + R11*S12 + R12*S22;
        const float M20 = R20*S00 + R21*S10 + R22*S20;
        const float M21 = R20*S01 + R21*S11 + R22*S21;
        const float M22 = R20*S02 + R21*S12 + R22*S22;

        // C = M*R^T
        const float C00 = M00*R00 + M01*R01 + M02*R02;
        const float C01 = M00*R10 + M01*R11 + M02*R12;
        const float C02 = M00*R20 + M01*R21 + M02*R22;
        const float C10 = M10*R00 + M11*R01 + M12*R02;
        const float C11 = M10*R10 + M11*R11 + M12*R12;
        const float C12 = M10*R20 + M11*R21 + M12*R22;
        const float C20 = M20*R00 + M21*R01 + M22*R02;
        const float C21 = M20*R10 + M21*R11 + M22*R12;
        const float C22 = M20*R20 + M21*R21 + M22*R22;

        // JC = J*C (2x3)
        const float JC00 = J00*C00 + J01*C10 + J02*C20;
        const float JC01 = J00*C01 + J01*C11 + J02*C21;
        const float JC02 = J00*C02 + J01*C12 + J02*C22;
        const float JC10 = J10*C00 + J11*C10 + J12*C20;
        const float JC11 = J10*C01 + J11*C11 + J12*C21;
        const float JC12 = J10*C02 + J11*C12 + J12*C22;

        // V = JC*J^T + EPS*I
        const float a = JC00*J00 + JC01*J01 + JC02*J02 + G_EPS;
        const float bb= JC00*J10 + JC01*J11 + JC02*J12;
        const float c = JC10*J00 + JC11*J01 + JC12*J02;
        const float d = JC10*J10 + JC11*J11 + JC12*J12 + G_EPS;

        const float det = a*d - bb*c;
        const float inv_det = 1.0f / det;
        const bool valid = (depth > 1.0f) && (depth < 50.0f);
        const float normalizer = 0.15915494309189535f / sqrtf(det);
        const float premult = valid ? (opacities[gi] * normalizer) : 0.0f;

        // cull radius from lambda_min of ln-domain conic Q = 0.5*invdet*[[d,.],[.,a]]
        const float tm   = 0.25f * inv_det * (a + d);
        const float detQ = 0.25f * inv_det * inv_det * (a*d - 0.25f*(bb+c)*(bb+c));
        const float lmin = tm - sqrtf(fmaxf(tm*tm - detQ, 0.0f));
        float rr2;
        const float ratio = premult * CULL_INV_EPS;   // premult/eps
        if (ratio > 1.0f && lmin > 0.0f) {
            const float r2c = logf(ratio) / lmin;     // radius^2 where contrib = eps
            const float rr  = sqrtf(r2c) + TILE_RAD;
            rr2 = rr * rr;
        } else {
            rr2 = -1.0f;   // never kept
        }

        const float c5 = (premult > 0.0f) ? __log2f(premult) : -1e30f;

        ((float2*)gp)[r] = make_float2(mx, my);
        gp[2048 + r] = rr2;

        float* o = gp + 3072 + r*12;
        *(float4*)(o + 0) = make_float4(mx, my,
                                        -0.5f * d * inv_det * LOG2E,
                                         0.5f * (bb + c) * inv_det * LOG2E);
        *(float4*)(o + 4) = make_float4(-0.5f * a * inv_det * LOG2E,
                                        c5,
                                        colors[gi*3+0],
                                        colors[gi*3+1]);
        *(float4*)(o + 8) = make_float4(colors[gi*3+2], 0.0f, 0.0f, 0.0f);
    }
}

// ---------------------------------------------------------------------------
// Kernel 2: per-tile cull+compact+composite.
// Grid 1024 blocks x 512 threads. Block = one 8x8 pixel tile.
// Thread t: pixel p = t&63 (one wave = one segment), segment s = t>>6 (0..7).
// Segment s composites survivors [s*seg, min((s+1)*seg,total)); combined with
// C = C0 + T0*(C1 + T1*(C2 + ...)).
// ---------------------------------------------------------------------------
__global__ __launch_bounds__(512) void render_kernel(
    const float* __restrict__ gp, float* __restrict__ out)
{
    __shared__ alignas(16) float sgrec[N_G * 12];  // 48 KB worst case
    __shared__ float comb[7][4][64];               // 7 KB
    __shared__ int wc[8];

    const int t    = threadIdx.x;
    const int tile = blockIdx.x;
    const int lane = t & 63;
    const int w    = t >> 6;
    const float cx = (float)((tile & 31) << 3) + 3.5f;
    const float cy = (float)((tile >> 5) << 3) + 3.5f;

    const float2* mean2 = (const float2*)gp;
    const float*  rr2a  = gp + 2048;
    const float*  rec   = gp + 3072;

    // --- cull + order-preserving compact + stage to LDS ---
    int total = 0;
    #pragma unroll
    for (int rnd = 0; rnd < 2; ++rnd) {
        const int g = rnd * 512 + t;
        const float2 m  = mean2[g];
        const float rr2 = rr2a[g];
        const float dx = m.x - cx, dy = m.y - cy;
        const bool keep = fmaf(dx, dx, dy*dy) <= rr2;
        const unsigned long long bm = __ballot(keep);
        if (lane == 0) wc[w] = __popcll(bm);
        __syncthreads();
        int baseW = 0, sumAll = 0;
        #pragma unroll
        for (int i = 0; i < 8; ++i) {
            const int c = wc[i];
            if (i < w) baseW += c;
            sumAll += c;
        }
        if (keep) {
            const int pos = total + baseW + __popcll(bm & ((1ull << lane) - 1ull));
            const float4* s4 = (const float4*)(rec + g*12);
            const float4 q0 = s4[0], q1 = s4[1], q2 = s4[2];
            float4* dst = (float4*)&sgrec[pos * 12];
            dst[0] = q0; dst[1] = q1; dst[2] = q2;
        }
        total += sumAll;
        __syncthreads();   // wc reuse + sgrec visibility
    }

    // --- composite survivors [k0,k1) for this segment ---
    const int p  = lane;        // pixel within 8x8 tile
    const int s  = w;           // segment 0..7
    const int px = ((tile & 31) << 3) + (p & 7);
    const int py = ((tile >> 5) << 3) + (p >> 3);
    const float fpx = (float)px, fpy = (float)py;

    const int seg = (total + 7) >> 3;
    const int k0 = s * seg;
    const int k1 = (k0 + seg < total) ? (k0 + seg) : total;

    float T = 1.0f, cr = 0.0f, cg = 0.0f, cb = 0.0f;
    for (int k = k0; k < k1; ++k) {
        const float* g = &sgrec[k * 12];
        const float4 a0 = *(const float4*)(g + 0);  // mx,my,c2,c3
        const float4 a1 = *(const float4*)(g + 4);  // c4,c5,r,g
        const float bcol = g[8];
        const float dx = fpx - a0.x;
        const float dy = fpy - a0.y;
        const float t1 = fmaf(a0.w, dy, a0.z * dx);     // c2*dx + c3*dy
        const float h  = fmaf(a1.x, dy*dy, a1.y);       // c4*dy^2 + log2(pm)
        const float P2 = fmaf(dx, t1, h);
        const float alpha = __builtin_amdgcn_exp2f(P2); // = pm * gaussian
        const float wgt = T * alpha;
        cr = fmaf(wgt, a1.z, cr);
        cg = fmaf(wgt, a1.w, cg);
        cb = fmaf(wgt, bcol, cb);
        T  = fmaf(-alpha, T, T);
    }

    if (s > 0) {
        comb[s-1][0][p] = T;
        comb[s-1][1][p] = cr;
        comb[s-1][2][p] = cg;
        comb[s-1][3][p] = cb;
    }
    __syncthreads();

    if (s == 0) {
        #pragma unroll
        for (int si = 0; si < 7; ++si) {
            cr = fmaf(T, comb[si][1][p], cr);
            cg = fmaf(T, comb[si][2][p], cg);
            cb = fmaf(T, comb[si][3][p], cb);
            T *= comb[si][0][p];
        }
        const int pid = py * IMG_W + px;
        out[pid*3 + 0] = cr;
        out[pid*3 + 1] = cg;
        out[pid*3 + 2] = cb;
    }
}

extern "C" void kernel_launch(void* const* d_in, const int* in_sizes, int n_in,
                              void* d_out, int out_size, void* d_ws, size_t ws_size,
                              hipStream_t stream) {
    const float* means3D   = (const float*)d_in[0];
    const float* covs3d    = (const float*)d_in[1];
    const float* colors    = (const float*)d_in[2];
    const float* opacities = (const float*)d_in[3];
    const float* Km        = (const float*)d_in[4];
    const float* Rm        = (const float*)d_in[5];
    const float* tv        = (const float*)d_in[6];

    float* gp = (float*)d_ws;   // 60 KB used

    hipLaunchKernelGGL(prep_sort_kernel, dim3(16), dim3(256), 0, stream,
                       means3D, covs3d, colors, opacities, Km, Rm, tv, gp);
    hipLaunchKernelGGL(render_kernel, dim3(1024), dim3(512), 0, stream,
                       gp, (float*)d_out);
}

// Round 5
// 21.255 us; speedup vs baseline: 4.3760x; 1.0739x over previous
//
#include <hip/hip_runtime.h>
#include <hip/hip_fp16.h>
#include <math.h>

#define N_G   1024
#define IMG_H 256
#define IMG_W 256
#define G_EPS 1e-4f
#define LOG2E 1.4426950408889634f
#define TILE_RAD 4.9497475f    // 3.5*sqrt(2): max pixel distance from 8x8 tile center
#define CULL_INV_EPS 1.0e6f    // 1/eps, eps = 1e-6 contribution cutoff

// ws layout (floats):
//   gp[0    ..2047]  : float2 mean[1024]   (sorted order)
//   gp[2048 ..3071]  : float  rr2[1024]    (cull radius^2, incl. TILE_RAD)
//   gp[3072 ..11263] : float  rec[1024][8]:
//     [0] mean_x [1] mean_y
//     [2] c2 = -0.5*d*invdet*LOG2E     (dx^2 coeff, log2 domain)
//     [3] c3 = +0.5*(b+c)*invdet*LOG2E (dx*dy coeff)
//     [4] c4 = -0.5*a*invdet*LOG2E     (dy^2 coeff)
//     [5] c5 = log2(premult)           (folded into exponent)
//     [6] r,g packed fp16x2  [7] b (fp32)
// ---------------------------------------------------------------------------
__global__ __launch_bounds__(256) void prep_sort_kernel(
    const float* __restrict__ means3D,
    const float* __restrict__ covs3d,
    const float* __restrict__ colors,
    const float* __restrict__ opacities,
    const float* __restrict__ Km,
    const float* __restrict__ Rm,
    const float* __restrict__ tv,
    float* __restrict__ gp)
{
    __shared__ alignas(16) float sd[N_G];
    __shared__ int pr[4][64];

    const int t = threadIdx.x;
    const int b = blockIdx.x;

    const float R20=Rm[6],R21=Rm[7],R22=Rm[8];
    const float t2=tv[2];

    // phase 1: all 1024 depths, 4 per thread
    #pragma unroll
    for (int k = 0; k < 4; ++k) {
        const int g = t + 256*k;
        const float m0 = means3D[g*3+0], m1 = means3D[g*3+1], m2 = means3D[g*3+2];
        sd[g] = fmaxf(R20*m0 + R21*m1 + R22*m2 + t2, 1.0f);
    }
    __syncthreads();

    // phase 2: partial stable ranks (thread t: gaussian li=t&63, quarter q=t>>6)
    const int li = t & 63;
    const int q  = t >> 6;
    const int i  = b*64 + li;
    const float di = sd[i];
    int rank = 0;
    const int j0 = q*256;
    for (int j = j0; j < j0 + 256; j += 4) {
        const float4 d4 = *(const float4*)&sd[j];
        rank += (d4.x < di) || (d4.x == di && (j+0) < i);
        rank += (d4.y < di) || (d4.y == di && (j+1) < i);
        rank += (d4.z < di) || (d4.z == di && (j+2) < i);
        rank += (d4.w < di) || (d4.w == di && (j+3) < i);
    }
    pr[q][li] = rank;
    __syncthreads();

    // phase 3: first 64 threads: full projection + record at sorted position
    if (t < 64) {
        const int gi = b*64 + t;
        const int r  = pr[0][t] + pr[1][t] + pr[2][t] + pr[3][t];

        const float m0 = means3D[gi*3+0], m1 = means3D[gi*3+1], m2 = means3D[gi*3+2];
        const float R00=Rm[0],R01=Rm[1],R02=Rm[2];
        const float R10=Rm[3],R11=Rm[4],R12=Rm[5];
        const float t0=tv[0],t1=tv[1];

        const float camx = R00*m0 + R01*m1 + R02*m2 + t0;
        const float camy = R10*m0 + R11*m1 + R12*m2 + t1;
        const float camz = R20*m0 + R21*m1 + R22*m2 + t2;
        const float depth = fmaxf(camz, 1.0f);

        const float K00=Km[0],K01=Km[1],K02=Km[2];
        const float K10=Km[3],K11=Km[4],K12=Km[5];
        const float K20=Km[6],K21=Km[7],K22=Km[8];

        const float u = K00*camx + K01*camy + K02*camz;
        const float v = K10*camx + K11*camy + K12*camz;
        const float z = K20*camx + K21*camy + K22*camz;

        const float mx = u / z;
        const float my = v / z;

        const float inv_z2 = 1.0f / (z*z);
        const float J00 = K00/z - u*inv_z2;
        const float J01 = K01/z - v*inv_z2;
        const float J02 = -u*inv_z2;
        const float J10 = K10/z - u*inv_z2;
        const float J11 = K11/z - v*inv_z2;
        const float J12 = -v*inv_z2;

        const float* S = covs3d + gi*9;
        const float S00=S[0],S01=S[1],S02=S[2];
        const float S10=S[3],S11=S[4],S12=S[5];
        const float S20=S[6],S21=S[7],S22=S[8];

        // M = R*S
        const float M00 = R00*S00 + R01*S10 + R02*S20;
        const float M01 = R00*S01 + R01*S11 + R02*S21;
        const float M02 = R00*S02 + R01*S12 + R02*S22;
        const float M10 = R10*S00 + R11*S10 + R12*S20;
        const float M11 = R10*S01 + R11*S11 + R12*S21;
        const float M12 = R10*S02 + R11*S12 + R12*S22;
        const float M20 = R20*S00 + R21*S10 + R22*S20;
        const float M21 = R20*S01 + R21*S11 + R22*S21;
        const float M22 = R20*S02 + R21*S12 + R22*S22;

        // C = M*R^T
        const float C00 = M00*R00 + M01*R01 + M02*R02;
        const float C01 = M00*R10 + M01*R11 + M02*R12;
        const float C02 = M00*R20 + M01*R21 + M02*R22;
        const float C10 = M10*R00 + M11*R01 + M12*R02;
        const float C11 = M10*R10 + M11*R11 + M12*R12;
        const float C12 = M10*R20 + M11*R21 + M12*R22;
        const float C20 = M20*R00 + M21*R01 + M22*R02;
        const float C21 = M20*R10 + M21*R11 + M22*R12;
        const float C22 = M20*R20 + M21*R21 + M22*R22;

        // JC = J*C (2x3)
        const float JC00 = J00*C00 + J01*C10 + J02*C20;
        const float JC01 = J00*C01 + J01*C11 + J02*C21;
        const float JC02 = J00*C02 + J01*C12 + J02*C22;
        const float JC10 = J10*C00 + J11*C10 + J12*C20;
        const float JC11 = J10*C01 + J11*C11 + J12*C21;
        const float JC12 = J10*C02 + J11*C12 + J12*C22;

        // V = JC*J^T + EPS*I
        const float a = JC00*J00 + JC01*J01 + JC02*J02 + G_EPS;
        const float bb= JC00*J10 + JC01*J11 + JC02*J12;
        const float c = JC10*J00 + JC11*J01 + JC12*J02;
        const float d = JC10*J10 + JC11*J11 + JC12*J12 + G_EPS;

        const float det = a*d - bb*c;
        const float inv_det = 1.0f / det;
        const bool valid = (depth > 1.0f) && (depth < 50.0f);
        const float normalizer = 0.15915494309189535f / sqrtf(det);
        const float premult = valid ? (opacities[gi] * normalizer) : 0.0f;

        // cull radius from lambda_min of ln-domain conic Q = 0.5*invdet*[[d,.],[.,a]]
        const float tm   = 0.25f * inv_det * (a + d);
        const float detQ = 0.25f * inv_det * inv_det * (a*d - 0.25f*(bb+c)*(bb+c));
        const float lmin = tm - sqrtf(fmaxf(tm*tm - detQ, 0.0f));
        float rr2;
        const float ratio = premult * CULL_INV_EPS;   // premult/eps
        if (ratio > 1.0f && lmin > 0.0f) {
            const float r2c = logf(ratio) / lmin;     // radius^2 where contrib = eps
            const float rr  = sqrtf(r2c) + TILE_RAD;
            rr2 = rr * rr;
        } else {
            rr2 = -1.0f;   // never kept
        }

        const float c5 = (premult > 0.0f) ? __log2f(premult) : -1e30f;

        ((float2*)gp)[r] = make_float2(mx, my);
        gp[2048 + r] = rr2;

        __half2 rg = __floats2half2_rn(colors[gi*3+0], colors[gi*3+1]);
        const float rgf = __uint_as_float(*reinterpret_cast<unsigned*>(&rg));

        float* o = gp + 3072 + r*8;
        *(float4*)(o + 0) = make_float4(mx, my,
                                        -0.5f * d * inv_det * LOG2E,
                                         0.5f * (bb + c) * inv_det * LOG2E);
        *(float4*)(o + 4) = make_float4(-0.5f * a * inv_det * LOG2E,
                                        c5,
                                        rgf,
                                        colors[gi*3+2]);
    }
}

// ---------------------------------------------------------------------------
// Kernel 2: per-tile cull+compact+composite.
// Grid 1024 blocks x 512 threads. Block = one 8x8 pixel tile.
// Thread t: pixel p = t&63 (one wave = one segment), segment s = t>>6 (0..7).
// Segment s composites survivors [s*seg, min((s+1)*seg,total)); combined with
// C = C0 + T0*(C1 + T1*(C2 + ...)).
// LDS: 32KB records + 7KB combine -> 4 blocks/CU, all 1024 blocks resident.
// ---------------------------------------------------------------------------
__global__ __launch_bounds__(512, 8) void render_kernel(
    const float* __restrict__ gp, float* __restrict__ out)
{
    __shared__ alignas(16) float sgrec[N_G * 8];   // 32 KB worst case
    __shared__ float comb[7][4][64];               // 7 KB
    __shared__ int wc[8];

    const int t    = threadIdx.x;
    const int tile = blockIdx.x;
    const int lane = t & 63;
    const int w    = t >> 6;
    const float cx = (float)((tile & 31) << 3) + 3.5f;
    const float cy = (float)((tile >> 5) << 3) + 3.5f;

    const float2* mean2 = (const float2*)gp;
    const float*  rr2a  = gp + 2048;
    const float*  rec   = gp + 3072;

    // --- cull + order-preserving compact + stage to LDS ---
    int total = 0;
    #pragma unroll
    for (int rnd = 0; rnd < 2; ++rnd) {
        const int g = rnd * 512 + t;
        const float2 m  = mean2[g];
        const float rr2 = rr2a[g];
        const float dx = m.x - cx, dy = m.y - cy;
        const bool keep = fmaf(dx, dx, dy*dy) <= rr2;
        const unsigned long long bm = __ballot(keep);
        if (lane == 0) wc[w] = __popcll(bm);
        __syncthreads();
        int baseW = 0, sumAll = 0;
        #pragma unroll
        for (int i = 0; i < 8; ++i) {
            const int c = wc[i];
            if (i < w) baseW += c;
            sumAll += c;
        }
        if (keep) {
            const int pos = total + baseW + __popcll(bm & ((1ull << lane) - 1ull));
            const float4* s4 = (const float4*)(rec + g*8);
            const float4 q0 = s4[0], q1 = s4[1];
            float4* dst = (float4*)&sgrec[pos * 8];
            dst[0] = q0; dst[1] = q1;
        }
        total += sumAll;
        __syncthreads();   // wc reuse + sgrec visibility
    }

    // --- composite survivors [k0,k1) for this segment ---
    const int p  = lane;        // pixel within 8x8 tile
    const int s  = w;           // segment 0..7
    const int px = ((tile & 31) << 3) + (p & 7);
    const int py = ((tile >> 5) << 3) + (p >> 3);
    const float fpx = (float)px, fpy = (float)py;

    const int seg = (total + 7) >> 3;
    const int k0 = s * seg;
    const int k1 = (k0 + seg < total) ? (k0 + seg) : total;

    float T = 1.0f, cr = 0.0f, cg = 0.0f, cb = 0.0f;
    for (int k = k0; k < k1; ++k) {
        const float4* g4 = (const float4*)&sgrec[k * 8];
        const float4 a0 = g4[0];  // mx,my,c2,c3
        const float4 a1 = g4[1];  // c4,c5,rg16,b
        const float dx = fpx - a0.x;
        const float dy = fpy - a0.y;
        const float t1 = fmaf(a0.w, dy, a0.z * dx);     // c2*dx + c3*dy
        const float h  = fmaf(a1.x, dy*dy, a1.y);       // c4*dy^2 + log2(pm)
        const float P2 = fmaf(dx, t1, h);
        const float alpha = __builtin_amdgcn_exp2f(P2); // = pm * gaussian
        const float wgt = T * alpha;
        unsigned rgbits = __float_as_uint(a1.z);
        const float2 rg = __half22float2(*reinterpret_cast<__half2*>(&rgbits));
        cr = fmaf(wgt, rg.x, cr);
        cg = fmaf(wgt, rg.y, cg);
        cb = fmaf(wgt, a1.w, cb);
        T  = fmaf(-alpha, T, T);
    }

    if (s > 0) {
        comb[s-1][0][p] = T;
        comb[s-1][1][p] = cr;
        comb[s-1][2][p] = cg;
        comb[s-1][3][p] = cb;
    }
    __syncthreads();

    if (s == 0) {
        #pragma unroll
        for (int si = 0; si < 7; ++si) {
            cr = fmaf(T, comb[si][1][p], cr);
            cg = fmaf(T, comb[si][2][p], cg);
            cb = fmaf(T, comb[si][3][p], cb);
            T *= comb[si][0][p];
        }
        const int pid = py * IMG_W + px;
        out[pid*3 + 0] = cr;
        out[pid*3 + 1] = cg;
        out[pid*3 + 2] = cb;
    }
}

extern "C" void kernel_launch(void* const* d_in, const int* in_sizes, int n_in,
                              void* d_out, int out_size, void* d_ws, size_t ws_size,
                              hipStream_t stream) {
    const float* means3D   = (const float*)d_in[0];
    const float* covs3d    = (const float*)d_in[1];
    const float* colors    = (const float*)d_in[2];
    const float* opacities = (const float*)d_in[3];
    const float* Km        = (const float*)d_in[4];
    const float* Rm        = (const float*)d_in[5];
    const float* tv        = (const float*)d_in[6];

    float* gp = (float*)d_ws;   // 45 KB used

    hipLaunchKernelGGL(prep_sort_kernel, dim3(16), dim3(256), 0, stream,
                       means3D, covs3d, colors, opacities, Km, Rm, tv, gp);
    hipLaunchKernelGGL(render_kernel, dim3(1024), dim3(512), 0, stream,
                       gp, (float*)d_out);
}

// Round 6
// 19.819 us; speedup vs baseline: 4.6929x; 1.0724x over previous
//
#include <hip/hip_runtime.h>
#include <hip/hip_fp16.h>
#include <math.h>

#define N_G   1024
#define IMG_H 256
#define IMG_W 256
#define G_EPS 1e-4f
#define LOG2E 1.4426950408889634f
#define TILE_HALF 3.5f         // pixel centers within 8x8 tile are <= 3.5 from center
#define CULL_INV_EPS 1.0e6f    // 1/eps, eps = 1e-6 contribution cutoff

// ws layout (floats):
//   gp[0    ..4095]  : float4 cull[1024]   (mx, my, hx+3.5, hy+3.5) sorted order
//   gp[4096 ..12287] : float  rec[1024][8]:
//     [0] mean_x [1] mean_y
//     [2] c2 = -0.5*d*invdet*LOG2E     (dx^2 coeff, log2 domain)
//     [3] c3 = +0.5*(b+c)*invdet*LOG2E (dx*dy coeff)
//     [4] c4 = -0.5*a*invdet*LOG2E     (dy^2 coeff)
//     [5] c5 = log2(premult)           (folded into exponent)
//     [6] r,g packed fp16x2  [7] b (fp32)
// ---------------------------------------------------------------------------
__global__ __launch_bounds__(256) void prep_sort_kernel(
    const float* __restrict__ means3D,
    const float* __restrict__ covs3d,
    const float* __restrict__ colors,
    const float* __restrict__ opacities,
    const float* __restrict__ Km,
    const float* __restrict__ Rm,
    const float* __restrict__ tv,
    float* __restrict__ gp)
{
    __shared__ alignas(16) float sd[N_G];
    __shared__ int pr[4][64];

    const int t = threadIdx.x;
    const int b = blockIdx.x;

    const float R20=Rm[6],R21=Rm[7],R22=Rm[8];
    const float t2=tv[2];

    // phase 1: all 1024 depths, 4 per thread
    #pragma unroll
    for (int k = 0; k < 4; ++k) {
        const int g = t + 256*k;
        const float m0 = means3D[g*3+0], m1 = means3D[g*3+1], m2 = means3D[g*3+2];
        sd[g] = fmaxf(R20*m0 + R21*m1 + R22*m2 + t2, 1.0f);
    }
    __syncthreads();

    // phase 2: partial stable ranks (thread t: gaussian li=t&63, quarter q=t>>6)
    const int li = t & 63;
    const int q  = t >> 6;
    const int i  = b*64 + li;
    const float di = sd[i];
    int rank = 0;
    const int j0 = q*256;
    for (int j = j0; j < j0 + 256; j += 4) {
        const float4 d4 = *(const float4*)&sd[j];
        rank += (d4.x < di) || (d4.x == di && (j+0) < i);
        rank += (d4.y < di) || (d4.y == di && (j+1) < i);
        rank += (d4.z < di) || (d4.z == di && (j+2) < i);
        rank += (d4.w < di) || (d4.w == di && (j+3) < i);
    }
    pr[q][li] = rank;
    __syncthreads();

    // phase 3: first 64 threads: full projection + record at sorted position
    if (t < 64) {
        const int gi = b*64 + t;
        const int r  = pr[0][t] + pr[1][t] + pr[2][t] + pr[3][t];

        const float m0 = means3D[gi*3+0], m1 = means3D[gi*3+1], m2 = means3D[gi*3+2];
        const float R00=Rm[0],R01=Rm[1],R02=Rm[2];
        const float R10=Rm[3],R11=Rm[4],R12=Rm[5];
        const float t0=tv[0],t1=tv[1];

        const float camx = R00*m0 + R01*m1 + R02*m2 + t0;
        const float camy = R10*m0 + R11*m1 + R12*m2 + t1;
        const float camz = R20*m0 + R21*m1 + R22*m2 + t2;
        const float depth = fmaxf(camz, 1.0f);

        const float K00=Km[0],K01=Km[1],K02=Km[2];
        const float K10=Km[3],K11=Km[4],K12=Km[5];
        const float K20=Km[6],K21=Km[7],K22=Km[8];

        const float u = K00*camx + K01*camy + K02*camz;
        const float v = K10*camx + K11*camy + K12*camz;
        const float z = K20*camx + K21*camy + K22*camz;

        const float mx = u / z;
        const float my = v / z;

        const float inv_z2 = 1.0f / (z*z);
        const float J00 = K00/z - u*inv_z2;
        const float J01 = K01/z - v*inv_z2;
        const float J02 = -u*inv_z2;
        const float J10 = K10/z - u*inv_z2;
        const float J11 = K11/z - v*inv_z2;
        const float J12 = -v*inv_z2;

        const float* S = covs3d + gi*9;
        const float S00=S[0],S01=S[1],S02=S[2];
        const float S10=S[3],S11=S[4],S12=S[5];
        const float S20=S[6],S21=S[7],S22=S[8];

        // M = R*S
        const float M00 = R00*S00 + R01*S10 + R02*S20;
        const float M01 = R00*S01 + R01*S11 + R02*S21;
        const float M02 = R00*S02 + R01*S12 + R02*S22;
        const float M10 = R10*S00 + R11*S10 + R12*S20;
        const float M11 = R10*S01 + R11*S11 + R12*S21;
        const float M12 = R10*S02 + R11*S12 + R12*S22;
        const float M20 = R20*S00 + R21*S10 + R22*S20;
        const float M21 = R20*S01 + R21*S11 + R22*S21;
        const float M22 = R20*S02 + R21*S12 + R22*S22;

        // C = M*R^T
        const float C00 = M00*R00 + M01*R01 + M02*R02;
        const float C01 = M00*R10 + M01*R11 + M02*R12;
        const float C02 = M00*R20 + M01*R21 + M02*R22;
        const float C10 = M10*R00 + M11*R01 + M12*R02;
        const float C11 = M10*R10 + M11*R11 + M12*R12;
        const float C12 = M10*R20 + M11*R21 + M12*R22;
        const float C20 = M20*R00 + M21*R01 + M22*R02;
        const float C21 = M20*R10 + M21*R11 + M22*R12;
        const float C22 = M20*R20 + M21*R21 + M22*R22;

        // JC = J*C (2x3)
        const float JC00 = J00*C00 + J01*C10 + J02*C20;
        const float JC01 = J00*C01 + J01*C11 + J02*C21;
        const float JC02 = J00*C02 + J01*C12 + J02*C22;
        const float JC10 = J10*C00 + J11*C10 + J12*C20;
        const float JC11 = J10*C01 + J11*C11 + J12*C21;
        const float JC12 = J10*C02 + J11*C12 + J12*C22;

        // V = JC*J^T + EPS*I
        const float a = JC00*J00 + JC01*J01 + JC02*J02 + G_EPS;
        const float bb= JC00*J10 + JC01*J11 + JC02*J12;
        const float c = JC10*J00 + JC11*J01 + JC12*J02;
        const float d = JC10*J10 + JC11*J11 + JC12*J12 + G_EPS;

        const float det = a*d - bb*c;
        const float inv_det = 1.0f / det;
        const bool valid = (depth > 1.0f) && (depth < 50.0f);
        const float normalizer = 0.15915494309189535f / sqrtf(det);
        const float premult = valid ? (opacities[gi] * normalizer) : 0.0f;

        // ln-domain conic Q = 0.5*invdet*[[d, -(b+c)/2],[-(b+c)/2, a]]
        // eps-level-set ellipse q(v)=L, L = ln(premult/eps).
        // AABB half-extents: hx = sqrt(L*Qyy/detQ), hy = sqrt(L*Qxx/detQ)
        const float Qxx  = 0.5f * inv_det * d;
        const float Qyy  = 0.5f * inv_det * a;
        const float detQ = 0.25f * inv_det * inv_det * (a*d - 0.25f*(bb+c)*(bb+c));
        float hx = -1.0f, hy = -1.0f;
        const float ratio = premult * CULL_INV_EPS;   // premult/eps
        if (ratio > 1.0f && detQ > 0.0f) {
            const float L = logf(ratio);
            const float s = L / detQ;
            hx = sqrtf(fmaxf(s * Qyy, 0.0f)) + TILE_HALF;
            hy = sqrtf(fmaxf(s * Qxx, 0.0f)) + TILE_HALF;
        }

        const float c5 = (premult > 0.0f) ? __log2f(premult) : -1e30f;

        ((float4*)gp)[r] = make_float4(mx, my, hx, hy);

        __half2 rg = __floats2half2_rn(colors[gi*3+0], colors[gi*3+1]);
        const float rgf = __uint_as_float(*reinterpret_cast<unsigned*>(&rg));

        float* o = gp + 4096 + r*8;
        *(float4*)(o + 0) = make_float4(mx, my,
                                        -0.5f * d * inv_det * LOG2E,
                                         0.5f * (bb + c) * inv_det * LOG2E);
        *(float4*)(o + 4) = make_float4(-0.5f * a * inv_det * LOG2E,
                                        c5,
                                        rgf,
                                        colors[gi*3+2]);
    }
}

// ---------------------------------------------------------------------------
// Kernel 2: per-tile cull+compact+composite.
// Grid 1024 blocks x 512 threads. Block = one 8x8 pixel tile, chosen via a
// load-balancing permutation: assuming blocks b, b+256, b+512, b+768 land on
// the same CU (round-robin), each CU gets {far-top, near(+16 col), near-mirror,
// far-bottom} tiles, flattening the radially-peaked survivor distribution.
// Thread t: pixel p = t&63, segment s = t>>6 (0..7); segments combined with
// C = C0 + T0*(C1 + T1*(C2 + ...)).
// ---------------------------------------------------------------------------
__global__ __launch_bounds__(512, 8) void render_kernel(
    const float* __restrict__ gp, float* __restrict__ out)
{
    __shared__ alignas(16) float sgrec[N_G * 8];   // 32 KB worst case
    __shared__ float comb[7][4][64];               // 7 KB
    __shared__ int wc[8];

    const int t    = threadIdx.x;
    const int lane = t & 63;
    const int w    = t >> 6;

    // block -> tile permutation for per-CU load balance
    const int bi = blockIdx.x;
    const int i  = bi & 255;
    const int qq = bi >> 8;
    const int x0 = i & 31;
    const int y0 = i >> 5;          // 0..7
    int tx, ty;
    switch (qq) {
        case 0:  tx = x0;             ty = y0;        break;  // rows 0-7   (far)
        case 1:  tx = (x0+16) & 31;   ty = y0 + 8;    break;  // rows 8-15  (near)
        case 2:  tx = (x0+16) & 31;   ty = 23 - y0;   break;  // rows 16-23 (near)
        default: tx = x0;             ty = 31 - y0;   break;  // rows 24-31 (far)
    }
    const float cx = (float)(tx << 3) + 3.5f;
    const float cy = (float)(ty << 3) + 3.5f;

    const float4* cull4 = (const float4*)gp;
    const float*  rec   = gp + 4096;

    // --- cull (AABB) + order-preserving compact + stage to LDS ---
    int total = 0;
    #pragma unroll
    for (int rnd = 0; rnd < 2; ++rnd) {
        const int g = rnd * 512 + t;
        const float4 cb = cull4[g];
        const bool keep = (fabsf(cb.x - cx) <= cb.z) & (fabsf(cb.y - cy) <= cb.w);
        const unsigned long long bm = __ballot(keep);
        if (lane == 0) wc[w] = __popcll(bm);
        __syncthreads();
        int baseW = 0, sumAll = 0;
        #pragma unroll
        for (int ii = 0; ii < 8; ++ii) {
            const int c = wc[ii];
            if (ii < w) baseW += c;
            sumAll += c;
        }
        if (keep) {
            const int pos = total + baseW + __popcll(bm & ((1ull << lane) - 1ull));
            const float4* s4 = (const float4*)(rec + g*8);
            const float4 q0 = s4[0], q1 = s4[1];
            float4* dst = (float4*)&sgrec[pos * 8];
            dst[0] = q0; dst[1] = q1;
        }
        total += sumAll;
        __syncthreads();   // wc reuse + sgrec visibility
    }

    // --- composite survivors [k0,k1) for this segment ---
    const int p  = lane;        // pixel within 8x8 tile
    const int s  = w;           // segment 0..7
    const int px = (tx << 3) + (p & 7);
    const int py = (ty << 3) + (p >> 3);
    const float fpx = (float)px, fpy = (float)py;

    const int seg = (total + 7) >> 3;
    const int k0 = s * seg;
    const int k1 = (k0 + seg < total) ? (k0 + seg) : total;

    float T = 1.0f, cr = 0.0f, cg = 0.0f, cb2 = 0.0f;
    for (int k = k0; k < k1; ++k) {
        const float4* g4 = (const float4*)&sgrec[k * 8];
        const float4 a0 = g4[0];  // mx,my,c2,c3
        const float4 a1 = g4[1];  // c4,c5,rg16,b
        const float dx = fpx - a0.x;
        const float dy = fpy - a0.y;
        const float t1 = fmaf(a0.w, dy, a0.z * dx);     // c2*dx + c3*dy
        const float h  = fmaf(a1.x, dy*dy, a1.y);       // c4*dy^2 + log2(pm)
        const float P2 = fmaf(dx, t1, h);
        const float alpha = __builtin_amdgcn_exp2f(P2); // = pm * gaussian
        const float wgt = T * alpha;
        unsigned rgbits = __float_as_uint(a1.z);
        const float2 rg = __half22float2(*reinterpret_cast<__half2*>(&rgbits));
        cr  = fmaf(wgt, rg.x, cr);
        cg  = fmaf(wgt, rg.y, cg);
        cb2 = fmaf(wgt, a1.w, cb2);
        T   = fmaf(-alpha, T, T);
    }

    if (s > 0) {
        comb[s-1][0][p] = T;
        comb[s-1][1][p] = cr;
        comb[s-1][2][p] = cg;
        comb[s-1][3][p] = cb2;
    }
    __syncthreads();

    if (s == 0) {
        #pragma unroll
        for (int si = 0; si < 7; ++si) {
            cr  = fmaf(T, comb[si][1][p], cr);
            cg  = fmaf(T, comb[si][2][p], cg);
            cb2 = fmaf(T, comb[si][3][p], cb2);
            T *= comb[si][0][p];
        }
        const int pid = py * IMG_W + px;
        out[pid*3 + 0] = cr;
        out[pid*3 + 1] = cg;
        out[pid*3 + 2] = cb2;
    }
}

extern "C" void kernel_launch(void* const* d_in, const int* in_sizes, int n_in,
                              void* d_out, int out_size, void* d_ws, size_t ws_size,
                              hipStream_t stream) {
    const float* means3D   = (const float*)d_in[0];
    const float* covs3d    = (const float*)d_in[1];
    const float* colors    = (const float*)d_in[2];
    const float* opacities = (const float*)d_in[3];
    const float* Km        = (const float*)d_in[4];
    const float* Rm        = (const float*)d_in[5];
    const float* tv        = (const float*)d_in[6];

    float* gp = (float*)d_ws;   // 48 KB used

    hipLaunchKernelGGL(prep_sort_kernel, dim3(16), dim3(256), 0, stream,
                       means3D, covs3d, colors, opacities, Km, Rm, tv, gp);
    hipLaunchKernelGGL(render_kernel, dim3(1024), dim3(512), 0, stream,
                       gp, (float*)d_out);
}